// Round 6
// baseline (401.312 us; speedup 1.0000x reference)
//
#include <hip/hip_runtime.h>

#define TT 512

typedef __attribute__((ext_vector_type(8))) short short8;
typedef __attribute__((ext_vector_type(4))) float floatx4;

// raw workgroup barrier: NO vmcnt/lgkmcnt drain. LDS pipe is in-order per CU,
// so pre-barrier ds_writes are visible to post-barrier ds_reads; asm memory
// fences stop the compiler from moving LDS ops across the interval boundary.
#define BAR() do { __asm__ volatile("" ::: "memory"); \
                   __builtin_amdgcn_s_barrier();      \
                   __asm__ volatile("" ::: "memory"); } while (0)

__device__ __forceinline__ unsigned short f2bf(float f) {  // RTNE (weights only)
    unsigned u = __float_as_uint(f);
    return (unsigned short)((u + 0x7FFFu + ((u >> 16) & 1u)) >> 16);
}
__device__ __forceinline__ float bf2f(unsigned short b) {
    return __uint_as_float(((unsigned)b) << 16);
}
__device__ __forceinline__ float fast_tanh(float z) {
    const float e = __expf(2.f * z);
    return 1.f - __fdividef(2.f, e + 1.f);
}
__device__ __forceinline__ float f4e(const float4& v, int r) {
    return (r == 0) ? v.x : (r == 1) ? v.y : (r == 2) ? v.z : v.w;
}

// Split-layer pipelined MFMA RNN: one LAYER per barrier interval.
//   even interval (step s): compute h0(s)=tanh(W0·h0(s-1)+x(s)Wih0+b0);
//                           prefetch h1(s-2) for next interval
//   odd  interval         : compute h1(s-1)=tanh(Wi1·h0(s-1)+W1·h1(s-2)+b1);
//                           prefetch h0(s) (serves L0-(s+1) AND L1-s)
// All reads issued one interval before use -> latency hidden under compute.
// h planes single-buffered in LDS (in-order LDS FIFO makes WAR/RAW safe across
// raw barriers). Split-3 bf16 (Whi*hhi+Whi*hlo+Wlo*hhi) ~ fp32 precision.
__global__ void __launch_bounds__(256, 1)
rnn2_mfma(const float* __restrict__ x,
          const float* __restrict__ W_ih0, const float* __restrict__ W_hh0,
          const float* __restrict__ b_ih0, const float* __restrict__ b_hh0,
          const float* __restrict__ W_ih1, const float* __restrict__ W_hh1,
          const float* __restrict__ b_ih1, const float* __restrict__ b_hh1,
          const float* __restrict__ W_fc, const float* __restrict__ b_fc,
          float* __restrict__ out)
{
    __shared__ short h0h[1024], h0l[1024];  // [chunk*512 + 128q + 8n + j]
    __shared__ short h1h[1024], h1l[1024];
    __shared__ float red[4][16];

    const int tid = threadIdx.x;
    const int lane = tid & 63;
    const int w = tid >> 6;
    const int n = lane & 15;
    const int q = lane >> 4;
    const int b0 = blockIdx.x * 16;

    // zero h1 planes (h1(-1) = 0); h0 written before first read
    for (int i = tid; i < 512; i += 256) {
        ((int*)h1h)[i] = 0;
        ((int*)h1l)[i] = 0;
    }

    // ---- static weight fragments (A-operand), rows [16w,16w+16) ----
    const int mrow = 16 * w + n;
    const int m4 = 16 * w + 4 * q;
    short8 w0h[2], w0l[2], wi1h[2], wi1l[2], w1h[2], w1l[2];
    auto mkfrag = [&](const float* p, short8& hi, short8& lo) {
#pragma unroll
        for (int j = 0; j < 8; ++j) {
            const float v = p[j];
            const unsigned short h = f2bf(v);
            hi[j] = (short)h;
            lo[j] = (short)f2bf(v - bf2f(h));
        }
    };
#pragma unroll
    for (int k = 0; k < 2; ++k) {
        mkfrag(W_hh0 + mrow * 64 + 32 * k + 8 * q, w0h[k], w0l[k]);
        mkfrag(W_ih1 + mrow * 64 + 32 * k + 8 * q, wi1h[k], wi1l[k]);
        mkfrag(W_hh1 + mrow * 64 + 32 * k + 8 * q, w1h[k], w1l[k]);
    }
    const float4 wih0v = *(const float4*)(W_ih0 + m4);
    float4 bv0 = *(const float4*)(b_ih0 + m4);
    { float4 t = *(const float4*)(b_hh0 + m4); bv0.x += t.x; bv0.y += t.y; bv0.z += t.z; bv0.w += t.w; }
    float4 bv1 = *(const float4*)(b_ih1 + m4);
    { float4 t = *(const float4*)(b_hh1 + m4); bv1.x += t.x; bv1.y += t.y; bv1.z += t.z; bv1.w += t.w; }
    const float4 wfcv = *(const float4*)(W_fc + m4);

    const int rbase = 128 * q + 8 * n;
    const int wbase = (2 * w + (q >> 1)) * 128 + 8 * n + 4 * (q & 1);

    const float* xp = x + (long)(b0 + n) * TT;
    const floatx4 zero4 = {0.f, 0.f, 0.f, 0.f};

    // tanh + truncation split + pack + LDS write
    auto epi_write = [&](const floatx4& A, const floatx4& B, const floatx4& C,
                         short* ph, short* pl) {
        unsigned tb[4]; float lo[4];
#pragma unroll
        for (int r = 0; r < 4; ++r) {
            const float h = fast_tanh((A[r] + B[r]) + C[r]);
            tb[r] = __float_as_uint(h) & 0xffff0000u;
            lo[r] = h - __uint_as_float(tb[r]);
        }
        uint2 hh, hl;
        hh.x = __builtin_amdgcn_perm(tb[1], tb[0], 0x07060302u);
        hh.y = __builtin_amdgcn_perm(tb[3], tb[2], 0x07060302u);
        hl.x = __builtin_amdgcn_perm(__float_as_uint(lo[1]), __float_as_uint(lo[0]), 0x07060302u);
        hl.y = __builtin_amdgcn_perm(__float_as_uint(lo[3]), __float_as_uint(lo[2]), 0x07060302u);
        *(uint2*)&ph[wbase] = hh;
        *(uint2*)&pl[wbase] = hl;
    };

    // ---- prologue: h0(0) = tanh(x(0)*Wih0 + b0), write, barrier ----
    {
        const float xv0 = xp[0];
        unsigned tb[4]; float lo[4];
#pragma unroll
        for (int r = 0; r < 4; ++r) {
            const float h = fast_tanh(__builtin_fmaf(xv0, f4e(wih0v, r), f4e(bv0, r)));
            tb[r] = __float_as_uint(h) & 0xffff0000u;
            lo[r] = h - __uint_as_float(tb[r]);
        }
        uint2 hh, hl;
        hh.x = __builtin_amdgcn_perm(tb[1], tb[0], 0x07060302u);
        hh.y = __builtin_amdgcn_perm(tb[3], tb[2], 0x07060302u);
        hl.x = __builtin_amdgcn_perm(__float_as_uint(lo[1]), __float_as_uint(lo[0]), 0x07060302u);
        hl.y = __builtin_amdgcn_perm(__float_as_uint(lo[3]), __float_as_uint(lo[2]), 0x07060302u);
        *(uint2*)&h0h[wbase] = hh;
        *(uint2*)&h0l[wbase] = hl;
    }
    BAR();

    // prime: read h0(0) fragments
    short8 bh[2], bl[2];
#pragma unroll
    for (int k = 0; k < 2; ++k) {
        bh[k] = *(const short8*)&h0h[rbase + 512 * k];
        bl[k] = *(const short8*)&h0l[rbase + 512 * k];
    }
    float xv = xp[1];
    float xnext = xp[2];

    for (int s = 1; s < TT; ++s) {
        // ===== EVEN interval: compute L0-s; prefetch h1(s-2) =====
        short8 ch[2], cl[2];
#pragma unroll
        for (int k = 0; k < 2; ++k) {
            ch[k] = *(const short8*)&h1h[rbase + 512 * k];
            cl[k] = *(const short8*)&h1l[rbase + 512 * k];
        }
        floatx4 a0A = {__builtin_fmaf(xv, wih0v.x, bv0.x), __builtin_fmaf(xv, wih0v.y, bv0.y),
                       __builtin_fmaf(xv, wih0v.z, bv0.z), __builtin_fmaf(xv, wih0v.w, bv0.w)};
        floatx4 a0B = zero4, a0C = zero4;
#pragma unroll
        for (int k = 0; k < 2; ++k) {
            a0A = __builtin_amdgcn_mfma_f32_16x16x32_bf16(w0h[k], bh[k], a0A, 0, 0, 0);
            a0B = __builtin_amdgcn_mfma_f32_16x16x32_bf16(w0h[k], bl[k], a0B, 0, 0, 0);
            a0C = __builtin_amdgcn_mfma_f32_16x16x32_bf16(w0l[k], bh[k], a0C, 0, 0, 0);
        }
        epi_write(a0A, a0B, a0C, h0h, h0l);  // h0(s)
        BAR();

        // ===== ODD interval: compute L1-(s-1); prefetch h0(s) =====
        short8 nbh[2], nbl[2];
#pragma unroll
        for (int k = 0; k < 2; ++k) {
            nbh[k] = *(const short8*)&h0h[rbase + 512 * k];
            nbl[k] = *(const short8*)&h0l[rbase + 512 * k];
        }
        floatx4 a1A = {bv1.x, bv1.y, bv1.z, bv1.w};
        floatx4 a1B = zero4, a1C = zero4;
#pragma unroll
        for (int k = 0; k < 2; ++k) {
            a1A = __builtin_amdgcn_mfma_f32_16x16x32_bf16(wi1h[k], bh[k], a1A, 0, 0, 0);
            a1B = __builtin_amdgcn_mfma_f32_16x16x32_bf16(wi1h[k], bl[k], a1B, 0, 0, 0);
            a1C = __builtin_amdgcn_mfma_f32_16x16x32_bf16(wi1l[k], bh[k], a1C, 0, 0, 0);
            a1A = __builtin_amdgcn_mfma_f32_16x16x32_bf16(w1h[k], ch[k], a1A, 0, 0, 0);
            a1B = __builtin_amdgcn_mfma_f32_16x16x32_bf16(w1h[k], cl[k], a1B, 0, 0, 0);
            a1C = __builtin_amdgcn_mfma_f32_16x16x32_bf16(w1l[k], cl[k] - cl[k] + ch[k], a1C, 0, 0, 0);
        }
        epi_write(a1A, a1B, a1C, h1h, h1l);  // h1(s-1)
#pragma unroll
        for (int k = 0; k < 2; ++k) { bh[k] = nbh[k]; bl[k] = nbl[k]; }
        xv = xnext;
        xnext = xp[(s + 2) & (TT - 1)];
        BAR();
    }

    // ---- tail: h1(511) = tanh(Wi1·h0(511) + W1·h1(510) + b1) + FC dot ----
    float p;
    {
        short8 ch[2], cl[2];
#pragma unroll
        for (int k = 0; k < 2; ++k) {
            ch[k] = *(const short8*)&h1h[rbase + 512 * k];  // h1(510)
            cl[k] = *(const short8*)&h1l[rbase + 512 * k];
        }
        floatx4 a1A = {bv1.x, bv1.y, bv1.z, bv1.w};
        floatx4 a1B = zero4, a1C = zero4;
#pragma unroll
        for (int k = 0; k < 2; ++k) {
            a1A = __builtin_amdgcn_mfma_f32_16x16x32_bf16(wi1h[k], bh[k], a1A, 0, 0, 0);
            a1B = __builtin_amdgcn_mfma_f32_16x16x32_bf16(wi1h[k], bl[k], a1B, 0, 0, 0);
            a1C = __builtin_amdgcn_mfma_f32_16x16x32_bf16(wi1l[k], bh[k], a1C, 0, 0, 0);
            a1A = __builtin_amdgcn_mfma_f32_16x16x32_bf16(w1h[k], ch[k], a1A, 0, 0, 0);
            a1B = __builtin_amdgcn_mfma_f32_16x16x32_bf16(w1h[k], cl[k], a1B, 0, 0, 0);
            a1C = __builtin_amdgcn_mfma_f32_16x16x32_bf16(w1l[k], ch[k], a1C, 0, 0, 0);
        }
        p = 0.f;
#pragma unroll
        for (int r = 0; r < 4; ++r) {
            const float h = fast_tanh((a1A[r] + a1B[r]) + a1C[r]);
            p = __builtin_fmaf(h, f4e(wfcv, r), p);
        }
    }

    p += __shfl_xor(p, 16, 64);
    p += __shfl_xor(p, 32, 64);
    if (lane < 16) red[w][lane] = p;
    __syncthreads();
    if (w == 0 && lane < 16)
        out[b0 + lane] = red[0][lane] + red[1][lane] + red[2][lane] + red[3][lane] + b_fc[0];
}

extern "C" void kernel_launch(void* const* d_in, const int* in_sizes, int n_in,
                              void* d_out, int out_size, void* d_ws, size_t ws_size,
                              hipStream_t stream) {
    const float* x     = (const float*)d_in[0];
    const float* W_ih0 = (const float*)d_in[1];
    const float* W_hh0 = (const float*)d_in[2];
    const float* b_ih0 = (const float*)d_in[3];
    const float* b_hh0 = (const float*)d_in[4];
    const float* W_ih1 = (const float*)d_in[5];
    const float* W_hh1 = (const float*)d_in[6];
    const float* b_ih1 = (const float*)d_in[7];
    const float* b_hh1 = (const float*)d_in[8];
    const float* W_fc  = (const float*)d_in[9];
    const float* b_fc  = (const float*)d_in[10];
    float* out = (float*)d_out;

    rnn2_mfma<<<128, 256, 0, stream>>>(x, W_ih0, W_hh0, b_ih0, b_hh0,
                                       W_ih1, W_hh1, b_ih1, b_hh1,
                                       W_fc, b_fc, out);
}

// Round 7
// 334.692 us; speedup vs baseline: 1.1990x; 1.1990x over previous
//
#include <hip/hip_runtime.h>

#define TT 512

typedef __attribute__((ext_vector_type(8))) short short8;
typedef __attribute__((ext_vector_type(4))) float floatx4;

// raw workgroup barrier (no vmcnt/lgkmcnt drain); LDS FIFO is in-order per CU,
// validated by R6 (single-buffered cross-parity reads stayed bit-exact).
#define BAR() do { __asm__ volatile("" ::: "memory"); \
                   __builtin_amdgcn_s_barrier();      \
                   __asm__ volatile("" ::: "memory"); } while (0)

__device__ __forceinline__ unsigned short f2bf(float f) {  // RTNE (weights only)
    unsigned u = __float_as_uint(f);
    return (unsigned short)((u + 0x7FFFu + ((u >> 16) & 1u)) >> 16);
}
__device__ __forceinline__ float bf2f(unsigned short b) {
    return __uint_as_float(((unsigned)b) << 16);
}
__device__ __forceinline__ float fast_tanh(float z) {
    const float e = __expf(2.f * z);
    return 1.f - __fdividef(2.f, e + 1.f);
}
__device__ __forceinline__ float f4e(const float4& v, int r) {
    return (r == 0) ? v.x : (r == 1) ? v.y : (r == 2) ? v.z : v.w;
}

// Layer-split wave specialization: 512 threads = 8 waves = 2 waves/SIMD.
// Waves 0-3: L0 step s   : h0(s)   = tanh(W0·h0(s-1) + x(s)Wih0 + b0)
// Waves 4-7: L1 step s-1 : h1(s-1) = tanh(Wi1·h0(s-1) + W1·h1(s-2) + b1)
// One barrier per superstep; h planes double-buffered (cross-wave prod/cons).
// Split-3 bf16 (Whi*hhi + Whi*hlo + Wlo*hhi) ~ fp32; h split by truncation.
// Numerics identical to R4 kernel (absmax signature 4.8828e-4).
__global__ void __launch_bounds__(512, 1)
rnn2_mfma(const float* __restrict__ x,
          const float* __restrict__ W_ih0, const float* __restrict__ W_hh0,
          const float* __restrict__ b_ih0, const float* __restrict__ b_hh0,
          const float* __restrict__ W_ih1, const float* __restrict__ W_hh1,
          const float* __restrict__ b_ih1, const float* __restrict__ b_hh1,
          const float* __restrict__ W_fc, const float* __restrict__ b_fc,
          float* __restrict__ out)
{
    __shared__ short h0h[2][1024], h0l[2][1024];  // [parity][chunk*512+128q+8n+j]
    __shared__ short h1h[2][1024], h1l[2][1024];
    __shared__ float red[4][16];

    const int tid = threadIdx.x;
    const int lane = tid & 63;
    const int w = tid >> 6;          // 0..7
    const int wq = w & 3;            // M-slice index within the layer group
    const bool isL0 = (w < 4);
    const int n = lane & 15;
    const int q = lane >> 4;
    const int b0 = blockIdx.x * 16;

    // h1(-1) = 0 lives at parity 1 (read by L1 at s=1); 512 ints per plane
    if (tid < 512) {
        ((int*)&h1h[1][0])[tid] = 0;
        ((int*)&h1l[1][0])[tid] = 0;
    }

    const int mrow = 16 * wq + n;
    const int m4 = 16 * wq + 4 * q;
    const int rbase = 128 * q + 8 * n;
    const int wbase = (2 * wq + (q >> 1)) * 128 + 8 * n + 4 * (q & 1);

    // ---- per-group weight fragments ----
    short8 wAh[2], wAl[2], wBh[2], wBl[2];  // L0: A=W_hh0; L1: A=W_ih1, B=W_hh1
    auto mkfrag = [&](const float* p, short8& hi, short8& lo) {
#pragma unroll
        for (int j = 0; j < 8; ++j) {
            const float v = p[j];
            const unsigned short h = f2bf(v);
            hi[j] = (short)h;
            lo[j] = (short)f2bf(v - bf2f(h));
        }
    };
    float4 wih0v = {0, 0, 0, 0}, bv0 = {0, 0, 0, 0}, bv1 = {0, 0, 0, 0}, wfcv = {0, 0, 0, 0};
    if (isL0) {
#pragma unroll
        for (int k = 0; k < 2; ++k)
            mkfrag(W_hh0 + mrow * 64 + 32 * k + 8 * q, wAh[k], wAl[k]);
        wih0v = *(const float4*)(W_ih0 + m4);
        bv0 = *(const float4*)(b_ih0 + m4);
        { float4 t = *(const float4*)(b_hh0 + m4); bv0.x += t.x; bv0.y += t.y; bv0.z += t.z; bv0.w += t.w; }
    } else {
#pragma unroll
        for (int k = 0; k < 2; ++k) {
            mkfrag(W_ih1 + mrow * 64 + 32 * k + 8 * q, wAh[k], wAl[k]);
            mkfrag(W_hh1 + mrow * 64 + 32 * k + 8 * q, wBh[k], wBl[k]);
        }
        bv1 = *(const float4*)(b_ih1 + m4);
        { float4 t = *(const float4*)(b_hh1 + m4); bv1.x += t.x; bv1.y += t.y; bv1.z += t.z; bv1.w += t.w; }
        wfcv = *(const float4*)(W_fc + m4);
    }

    const float* xp = x + (long)(b0 + n) * TT;
    const floatx4 zero4 = {0.f, 0.f, 0.f, 0.f};

    // tanh + truncation split + pack + LDS write (identical math to R4)
    auto epi_write = [&](const floatx4& A, const floatx4& B, const floatx4& C,
                         short* ph, short* pl) {
        unsigned tb[4]; float lo[4];
#pragma unroll
        for (int r = 0; r < 4; ++r) {
            const float h = fast_tanh((A[r] + B[r]) + C[r]);
            tb[r] = __float_as_uint(h) & 0xffff0000u;
            lo[r] = h - __uint_as_float(tb[r]);
        }
        uint2 hh, hl;
        hh.x = __builtin_amdgcn_perm(tb[1], tb[0], 0x07060302u);
        hh.y = __builtin_amdgcn_perm(tb[3], tb[2], 0x07060302u);
        hl.x = __builtin_amdgcn_perm(__float_as_uint(lo[1]), __float_as_uint(lo[0]), 0x07060302u);
        hl.y = __builtin_amdgcn_perm(__float_as_uint(lo[3]), __float_as_uint(lo[2]), 0x07060302u);
        *(uint2*)&ph[wbase] = hh;
        *(uint2*)&pl[wbase] = hl;
    };

    // ---- prologue: L0 waves write h0(0) = tanh(x(0)Wih0 + b0) -> parity 0 ----
    float xv = 0.f, xnext = 0.f;
    if (isL0) {
        const float xv0 = xp[0];
        unsigned tb[4]; float lo[4];
#pragma unroll
        for (int r = 0; r < 4; ++r) {
            const float h = fast_tanh(__builtin_fmaf(xv0, f4e(wih0v, r), f4e(bv0, r)));
            tb[r] = __float_as_uint(h) & 0xffff0000u;
            lo[r] = h - __uint_as_float(tb[r]);
        }
        uint2 hh, hl;
        hh.x = __builtin_amdgcn_perm(tb[1], tb[0], 0x07060302u);
        hh.y = __builtin_amdgcn_perm(tb[3], tb[2], 0x07060302u);
        hl.x = __builtin_amdgcn_perm(__float_as_uint(lo[1]), __float_as_uint(lo[0]), 0x07060302u);
        hl.y = __builtin_amdgcn_perm(__float_as_uint(lo[3]), __float_as_uint(lo[2]), 0x07060302u);
        *(uint2*)&h0h[0][wbase] = hh;
        *(uint2*)&h0l[0][wbase] = hl;
        xv = xp[1];
        xnext = xp[2];
    }
    BAR();

    // L0 superstep: read h0[rp], compute h0(s), write h0[wp]
    auto stepL0 = [&](int rp, int wp, float xvv) {
        short8 bh[2], bl[2];
#pragma unroll
        for (int k = 0; k < 2; ++k) {
            bh[k] = *(const short8*)&h0h[rp][rbase + 512 * k];
            bl[k] = *(const short8*)&h0l[rp][rbase + 512 * k];
        }
        floatx4 a0A = {__builtin_fmaf(xvv, wih0v.x, bv0.x), __builtin_fmaf(xvv, wih0v.y, bv0.y),
                       __builtin_fmaf(xvv, wih0v.z, bv0.z), __builtin_fmaf(xvv, wih0v.w, bv0.w)};
        floatx4 a0B = zero4, a0C = zero4;
#pragma unroll
        for (int k = 0; k < 2; ++k) {
            a0A = __builtin_amdgcn_mfma_f32_16x16x32_bf16(wAh[k], bh[k], a0A, 0, 0, 0);
            a0B = __builtin_amdgcn_mfma_f32_16x16x32_bf16(wAh[k], bl[k], a0B, 0, 0, 0);
            a0C = __builtin_amdgcn_mfma_f32_16x16x32_bf16(wAl[k], bh[k], a0C, 0, 0, 0);
        }
        epi_write(a0A, a0B, a0C, &h0h[wp][0], &h0l[wp][0]);
    };

    // L1 superstep: read h0[rp0], h1[rp1], compute h1, write h1[wp1]
    auto stepL1 = [&](int rp0, int rp1, int wp1) {
        short8 bh[2], bl[2], ch[2], cl[2];
#pragma unroll
        for (int k = 0; k < 2; ++k) {
            bh[k] = *(const short8*)&h0h[rp0][rbase + 512 * k];
            bl[k] = *(const short8*)&h0l[rp0][rbase + 512 * k];
            ch[k] = *(const short8*)&h1h[rp1][rbase + 512 * k];
            cl[k] = *(const short8*)&h1l[rp1][rbase + 512 * k];
        }
        floatx4 a1A = {bv1.x, bv1.y, bv1.z, bv1.w};
        floatx4 a1B = zero4, a1C = zero4;
#pragma unroll
        for (int k = 0; k < 2; ++k) {
            a1A = __builtin_amdgcn_mfma_f32_16x16x32_bf16(wAh[k], bh[k], a1A, 0, 0, 0);
            a1B = __builtin_amdgcn_mfma_f32_16x16x32_bf16(wAh[k], bl[k], a1B, 0, 0, 0);
            a1C = __builtin_amdgcn_mfma_f32_16x16x32_bf16(wAl[k], bh[k], a1C, 0, 0, 0);
            a1A = __builtin_amdgcn_mfma_f32_16x16x32_bf16(wBh[k], ch[k], a1A, 0, 0, 0);
            a1B = __builtin_amdgcn_mfma_f32_16x16x32_bf16(wBh[k], cl[k], a1B, 0, 0, 0);
            a1C = __builtin_amdgcn_mfma_f32_16x16x32_bf16(wBl[k], ch[k], a1C, 0, 0, 0);
        }
        epi_write(a1A, a1B, a1C, &h1h[wp1][0], &h1l[wp1][0]);
    };

    // main loop: pairs (s odd, s+1 even), s = 1..509; tail s = 511
    for (int s = 1; s < 511; s += 2) {
        // odd s: L0 h0(s): rp=0,wp=1 ; L1 h1(s-1): rp0=0, rp1=1, wp1=0
        if (isL0) {
            stepL0(0, 1, xv);
            xv = xnext; xnext = xp[(s + 2) & (TT - 1)];
        } else {
            stepL1(0, 1, 0);
        }
        BAR();
        // even s+1: L0 h0(s+1): rp=1,wp=0 ; L1 h1(s): rp0=1, rp1=0, wp1=1
        if (isL0) {
            stepL0(1, 0, xv);
            xv = xnext; xnext = xp[(s + 3) & (TT - 1)];
        } else {
            stepL1(1, 0, 1);
        }
        BAR();
    }
    // s = 511 (odd): L0 h0(511) -> parity 1 ; L1 h1(510) -> parity 0
    if (isL0) stepL0(0, 1, xv);
    else      stepL1(0, 1, 0);
    BAR();

    // ---- tail: L1 waves compute h1(511) = tanh(Wi1·h0(511) + W1·h1(510) + b1)
    float p = 0.f;
    if (!isL0) {
        short8 bh[2], bl[2], ch[2], cl[2];
#pragma unroll
        for (int k = 0; k < 2; ++k) {
            bh[k] = *(const short8*)&h0h[1][rbase + 512 * k];  // h0(511), parity 1
            bl[k] = *(const short8*)&h0l[1][rbase + 512 * k];
            ch[k] = *(const short8*)&h1h[0][rbase + 512 * k];  // h1(510), parity 0
            cl[k] = *(const short8*)&h1l[0][rbase + 512 * k];
        }
        floatx4 a1A = {bv1.x, bv1.y, bv1.z, bv1.w};
        floatx4 a1B = zero4, a1C = zero4;
#pragma unroll
        for (int k = 0; k < 2; ++k) {
            a1A = __builtin_amdgcn_mfma_f32_16x16x32_bf16(wAh[k], bh[k], a1A, 0, 0, 0);
            a1B = __builtin_amdgcn_mfma_f32_16x16x32_bf16(wAh[k], bl[k], a1B, 0, 0, 0);
            a1C = __builtin_amdgcn_mfma_f32_16x16x32_bf16(wAl[k], bh[k], a1C, 0, 0, 0);
            a1A = __builtin_amdgcn_mfma_f32_16x16x32_bf16(wBh[k], ch[k], a1A, 0, 0, 0);
            a1B = __builtin_amdgcn_mfma_f32_16x16x32_bf16(wBh[k], cl[k], a1B, 0, 0, 0);
            a1C = __builtin_amdgcn_mfma_f32_16x16x32_bf16(wBl[k], ch[k], a1C, 0, 0, 0);
        }
#pragma unroll
        for (int r = 0; r < 4; ++r) {
            const float h = fast_tanh((a1A[r] + a1B[r]) + a1C[r]);
            p = __builtin_fmaf(h, f4e(wfcv, r), p);
        }
        p += __shfl_xor(p, 16, 64);
        p += __shfl_xor(p, 32, 64);
        if (lane < 16) red[wq][lane] = p;
    }
    __syncthreads();
    if (w == 4 && lane < 16)
        out[b0 + lane] = red[0][lane] + red[1][lane] + red[2][lane] + red[3][lane] + b_fc[0];
}

extern "C" void kernel_launch(void* const* d_in, const int* in_sizes, int n_in,
                              void* d_out, int out_size, void* d_ws, size_t ws_size,
                              hipStream_t stream) {
    const float* x     = (const float*)d_in[0];
    const float* W_ih0 = (const float*)d_in[1];
    const float* W_hh0 = (const float*)d_in[2];
    const float* b_ih0 = (const float*)d_in[3];
    const float* b_hh0 = (const float*)d_in[4];
    const float* W_ih1 = (const float*)d_in[5];
    const float* W_hh1 = (const float*)d_in[6];
    const float* b_ih1 = (const float*)d_in[7];
    const float* b_hh1 = (const float*)d_in[8];
    const float* W_fc  = (const float*)d_in[9];
    const float* b_fc  = (const float*)d_in[10];
    float* out = (float*)d_out;

    rnn2_mfma<<<128, 512, 0, stream>>>(x, W_ih0, W_hh0, b_ih0, b_hh0,
                                       W_ih1, W_hh1, b_ih1, b_hh1,
                                       W_fc, b_fc, out);
}

// Round 9
// 296.416 us; speedup vs baseline: 1.3539x; 1.1291x over previous
//
#include <hip/hip_runtime.h>

#define TT 512

typedef _Float16 half8 __attribute__((ext_vector_type(8)));
typedef __attribute__((ext_vector_type(4))) float floatx4;

// raw workgroup barrier (no vmcnt/lgkmcnt drain); LDS FIFO is in-order per CU,
// validated R6/R7 (cross-parity reads stayed bit-exact across 512 steps).
#define BAR() do { __asm__ volatile("" ::: "memory"); \
                   __builtin_amdgcn_s_barrier();      \
                   __asm__ volatile("" ::: "memory"); } while (0)

__device__ __forceinline__ float fast_tanh(float z) {
    const float e = __expf(2.f * z);
    return 1.f - __fdividef(2.f, e + 1.f);
}
__device__ __forceinline__ float f4e(const float4& v, int r) {
    return (r == 0) ? v.x : (r == 1) ? v.y : (r == 2) ? v.z : v.w;
}
// pack two fp32->fp16 (RTNE) into one dword: lo16 = a, hi16 = b
__device__ __forceinline__ unsigned pk16(float a, float b) {
    const unsigned ua = __builtin_bit_cast(unsigned short, (_Float16)a);
    const unsigned ub = __builtin_bit_cast(unsigned short, (_Float16)b);
    return ua | (ub << 16);
}

// Layer-split wave specialization (R7 structure), h in SINGLE fp16 plane.
// 512 threads = 8 waves = 2 waves/SIMD.
// Waves 0-3: L0 step s   : h0(s)   = tanh(W0·h0(s-1) + x(s)Wih0 + b0)
// Waves 4-7: L1 step s-1 : h1(s-1) = tanh(Wi1·h0(s-1) + W1·h1(s-2) + b1)
// One barrier per superstep; h planes double-buffered by parity.
// Weights split-2 fp16 (Whi + Wlo, residual ~2^-22); h stored fp16 RTNE
// (err <= 2^-12/step, predicted absmax ~1.6e-3 vs 2.85e-3 threshold).
__global__ void __launch_bounds__(512, 1)
rnn2_mfma(const float* __restrict__ x,
          const float* __restrict__ W_ih0, const float* __restrict__ W_hh0,
          const float* __restrict__ b_ih0, const float* __restrict__ b_hh0,
          const float* __restrict__ W_ih1, const float* __restrict__ W_hh1,
          const float* __restrict__ b_ih1, const float* __restrict__ b_hh1,
          const float* __restrict__ W_fc, const float* __restrict__ b_fc,
          float* __restrict__ out)
{
    __shared__ short h0f[2][1024];  // [parity][chunk*512 + 128q + 8n + j], fp16
    __shared__ short h1f[2][1024];
    __shared__ float red[4][16];

    const int tid = threadIdx.x;
    const int lane = tid & 63;
    const int w = tid >> 6;          // 0..7
    const int wq = w & 3;            // M-slice within the layer group
    const bool isL0 = (w < 4);
    const int n = lane & 15;
    const int q = lane >> 4;
    const int b0 = blockIdx.x * 16;

    // h1(-1) = 0 at parity 1 (read by L1 at s=1)
    if (tid < 512) ((int*)&h1f[1][0])[tid] = 0;

    const int mrow = 16 * wq + n;
    const int m4 = 16 * wq + 4 * q;
    const int rbase = 128 * q + 8 * n;
    const int wbase = (2 * wq + (q >> 1)) * 128 + 8 * n + 4 * (q & 1);

    // ---- per-group weight fragments, fp16 split-2 ----
    half8 wAh[2], wAl[2], wBh[2], wBl[2];  // L0: A=W_hh0; L1: A=W_ih1, B=W_hh1
    auto mkfrag = [&](const float* p, half8& hi, half8& lo) {
#pragma unroll
        for (int j = 0; j < 8; ++j) {
            const float v = p[j];
            const _Float16 h = (_Float16)v;      // RTNE
            hi[j] = h;
            lo[j] = (_Float16)(v - (float)h);
        }
    };
    float4 wih0v = {0, 0, 0, 0}, bv0 = {0, 0, 0, 0}, bv1 = {0, 0, 0, 0}, wfcv = {0, 0, 0, 0};
    if (isL0) {
#pragma unroll
        for (int k = 0; k < 2; ++k)
            mkfrag(W_hh0 + mrow * 64 + 32 * k + 8 * q, wAh[k], wAl[k]);
        wih0v = *(const float4*)(W_ih0 + m4);
        bv0 = *(const float4*)(b_ih0 + m4);
        { float4 t = *(const float4*)(b_hh0 + m4); bv0.x += t.x; bv0.y += t.y; bv0.z += t.z; bv0.w += t.w; }
    } else {
#pragma unroll
        for (int k = 0; k < 2; ++k) {
            mkfrag(W_ih1 + mrow * 64 + 32 * k + 8 * q, wAh[k], wAl[k]);
            mkfrag(W_hh1 + mrow * 64 + 32 * k + 8 * q, wBh[k], wBl[k]);
        }
        bv1 = *(const float4*)(b_ih1 + m4);
        { float4 t = *(const float4*)(b_hh1 + m4); bv1.x += t.x; bv1.y += t.y; bv1.z += t.z; bv1.w += t.w; }
        wfcv = *(const float4*)(W_fc + m4);
    }

    const float* xp = x + (long)(b0 + n) * TT;
    const floatx4 zero4 = {0.f, 0.f, 0.f, 0.f};

    // tanh + fp16 RTNE pack + LDS write (4 rows -> uint2)
    auto epi_write = [&](const floatx4& A, const floatx4& C, short* pf) {
        float h[4];
#pragma unroll
        for (int r = 0; r < 4; ++r) h[r] = fast_tanh(A[r] + C[r]);
        uint2 u;
        u.x = pk16(h[0], h[1]);
        u.y = pk16(h[2], h[3]);
        *(uint2*)&pf[wbase] = u;
    };

    // ---- prologue: L0 waves write h0(0) = tanh(x(0)Wih0 + b0) -> parity 0 ----
    float xv = 0.f, xnext = 0.f;
    if (isL0) {
        const float xv0 = xp[0];
        float h[4];
#pragma unroll
        for (int r = 0; r < 4; ++r)
            h[r] = fast_tanh(__builtin_fmaf(xv0, f4e(wih0v, r), f4e(bv0, r)));
        uint2 u;
        u.x = pk16(h[0], h[1]);
        u.y = pk16(h[2], h[3]);
        *(uint2*)&h0f[0][wbase] = u;
        xv = xp[1];
        xnext = xp[2];
    }
    BAR();

    // L0 superstep: read h0[rp], compute h0(s), write h0[wp]
    auto stepL0 = [&](int rp, int wp, float xvv) {
        half8 b[2];
#pragma unroll
        for (int k = 0; k < 2; ++k)
            b[k] = *(const half8*)&h0f[rp][rbase + 512 * k];
        floatx4 aA = {__builtin_fmaf(xvv, wih0v.x, bv0.x), __builtin_fmaf(xvv, wih0v.y, bv0.y),
                      __builtin_fmaf(xvv, wih0v.z, bv0.z), __builtin_fmaf(xvv, wih0v.w, bv0.w)};
        floatx4 aC = zero4;
#pragma unroll
        for (int k = 0; k < 2; ++k) {
            aA = __builtin_amdgcn_mfma_f32_16x16x32_f16(wAh[k], b[k], aA, 0, 0, 0);
            aC = __builtin_amdgcn_mfma_f32_16x16x32_f16(wAl[k], b[k], aC, 0, 0, 0);
        }
        epi_write(aA, aC, &h0f[wp][0]);
    };

    // L1 superstep: read h0[rp0], h1[rp1], compute h1, write h1[wp1]
    auto stepL1 = [&](int rp0, int rp1, int wp1) {
        half8 b[2], c[2];
#pragma unroll
        for (int k = 0; k < 2; ++k) {
            b[k] = *(const half8*)&h0f[rp0][rbase + 512 * k];
            c[k] = *(const half8*)&h1f[rp1][rbase + 512 * k];
        }
        floatx4 aA = {bv1.x, bv1.y, bv1.z, bv1.w};
        floatx4 aC = zero4;
#pragma unroll
        for (int k = 0; k < 2; ++k) {
            aA = __builtin_amdgcn_mfma_f32_16x16x32_f16(wAh[k], b[k], aA, 0, 0, 0);
            aC = __builtin_amdgcn_mfma_f32_16x16x32_f16(wAl[k], b[k], aC, 0, 0, 0);
        }
#pragma unroll
        for (int k = 0; k < 2; ++k) {
            aA = __builtin_amdgcn_mfma_f32_16x16x32_f16(wBh[k], c[k], aA, 0, 0, 0);
            aC = __builtin_amdgcn_mfma_f32_16x16x32_f16(wBl[k], c[k], aC, 0, 0, 0);
        }
        epi_write(aA, aC, &h1f[wp1][0]);
    };

    // main loop: pairs (s odd, s+1 even), s = 1..509; tail s = 511
    for (int s = 1; s < 511; s += 2) {
        if (isL0) {
            stepL0(0, 1, xv);
            xv = xnext; xnext = xp[(s + 2) & (TT - 1)];
        } else {
            stepL1(0, 1, 0);
        }
        BAR();
        if (isL0) {
            stepL0(1, 0, xv);
            xv = xnext; xnext = xp[(s + 3) & (TT - 1)];
        } else {
            stepL1(1, 0, 1);
        }
        BAR();
    }
    // s = 511 (odd): L0 h0(511) -> parity 1 ; L1 h1(510) -> parity 0
    if (isL0) stepL0(0, 1, xv);
    else      stepL1(0, 1, 0);
    BAR();

    // ---- tail: L1 waves compute h1(511) + FC dot ----
    float p = 0.f;
    if (!isL0) {
        half8 b[2], c[2];
#pragma unroll
        for (int k = 0; k < 2; ++k) {
            b[k] = *(const half8*)&h0f[1][rbase + 512 * k];  // h0(511), parity 1
            c[k] = *(const half8*)&h1f[0][rbase + 512 * k];  // h1(510), parity 0
        }
        floatx4 aA = {bv1.x, bv1.y, bv1.z, bv1.w};
        floatx4 aC = zero4;
#pragma unroll
        for (int k = 0; k < 2; ++k) {
            aA = __builtin_amdgcn_mfma_f32_16x16x32_f16(wAh[k], b[k], aA, 0, 0, 0);
            aC = __builtin_amdgcn_mfma_f32_16x16x32_f16(wAl[k], b[k], aC, 0, 0, 0);
            aA = __builtin_amdgcn_mfma_f32_16x16x32_f16(wBh[k], c[k], aA, 0, 0, 0);
            aC = __builtin_amdgcn_mfma_f32_16x16x32_f16(wBl[k], c[k], aC, 0, 0, 0);
        }
#pragma unroll
        for (int r = 0; r < 4; ++r) {
            const float h = fast_tanh(aA[r] + aC[r]);
            p = __builtin_fmaf(h, f4e(wfcv, r), p);
        }
        p += __shfl_xor(p, 16, 64);
        p += __shfl_xor(p, 32, 64);
        if (lane < 16) red[wq][lane] = p;
    }
    __syncthreads();
    if (w == 4 && lane < 16)
        out[b0 + lane] = red[0][lane] + red[1][lane] + red[2][lane] + red[3][lane] + b_fc[0];
}

extern "C" void kernel_launch(void* const* d_in, const int* in_sizes, int n_in,
                              void* d_out, int out_size, void* d_ws, size_t ws_size,
                              hipStream_t stream) {
    const float* x     = (const float*)d_in[0];
    const float* W_ih0 = (const float*)d_in[1];
    const float* W_hh0 = (const float*)d_in[2];
    const float* b_ih0 = (const float*)d_in[3];
    const float* b_hh0 = (const float*)d_in[4];
    const float* W_ih1 = (const float*)d_in[5];
    const float* W_hh1 = (const float*)d_in[6];
    const float* b_ih1 = (const float*)d_in[7];
    const float* b_hh1 = (const float*)d_in[8];
    const float* W_fc  = (const float*)d_in[9];
    const float* b_fc  = (const float*)d_in[10];
    float* out = (float*)d_out;

    rnn2_mfma<<<128, 512, 0, stream>>>(x, W_ih0, W_hh0, b_ih0, b_hh0,
                                       W_ih1, W_hh1, b_ih1, b_hh1,
                                       W_fc, b_fc, out);
}

// Round 10
// 285.951 us; speedup vs baseline: 1.4034x; 1.0366x over previous
//
#include <hip/hip_runtime.h>

#define TT 512

typedef _Float16 half8 __attribute__((ext_vector_type(8)));
typedef __attribute__((ext_vector_type(4))) float floatx4;

// raw workgroup barrier (no vmcnt/lgkmcnt drain); LDS FIFO is in-order per CU,
// validated R6-R9 (cross-parity reads stayed bit-exact across 512 steps).
#define BAR() do { __asm__ volatile("" ::: "memory"); \
                   __builtin_amdgcn_s_barrier();      \
                   __asm__ volatile("" ::: "memory"); } while (0)

__device__ __forceinline__ float fast_tanh(float z) {
    const float e = __expf(2.f * z);
    return 1.f - __fdividef(2.f, e + 1.f);
}
__device__ __forceinline__ float f4e(const float4& v, int r) {
    return (r == 0) ? v.x : (r == 1) ? v.y : (r == 2) ? v.z : v.w;
}
// pack two fp32->fp16 (RTNE) into one dword: lo16 = a, hi16 = b
__device__ __forceinline__ unsigned pk16(float a, float b) {
    const unsigned ua = __builtin_bit_cast(unsigned short, (_Float16)a);
    const unsigned ub = __builtin_bit_cast(unsigned short, (_Float16)b);
    return ua | (ub << 16);
}

// Layer-split wave specialization (R7/R9 structure); h AND W single fp16.
// 512 threads = 8 waves = 2 waves/SIMD.
// Waves 0-3: L0 step s   : h0(s)   = tanh(W0·h0(s-1) + x(s)Wih0 + b0)
// Waves 4-7: L1 step s-1 : h1(s-1) = tanh(Wi1·h0(s-1) + W1·h1(s-2) + b1)
// One barrier per superstep; h planes double-buffered by parity.
// fp16 weights (RTNE, no lo-correction): per-step preact err ~2^-11;
// predicted absmax ~1.5e-3 vs 2.85e-3 threshold. Accumulator chains split
// 2-deep (aA/aB) to shorten dependent MFMA latency.
__global__ void __launch_bounds__(512, 1)
rnn2_mfma(const float* __restrict__ x,
          const float* __restrict__ W_ih0, const float* __restrict__ W_hh0,
          const float* __restrict__ b_ih0, const float* __restrict__ b_hh0,
          const float* __restrict__ W_ih1, const float* __restrict__ W_hh1,
          const float* __restrict__ b_ih1, const float* __restrict__ b_hh1,
          const float* __restrict__ W_fc, const float* __restrict__ b_fc,
          float* __restrict__ out)
{
    __shared__ short h0f[2][1024];  // [parity][chunk*512 + 128q + 8n + j], fp16
    __shared__ short h1f[2][1024];
    __shared__ float red[4][16];

    const int tid = threadIdx.x;
    const int lane = tid & 63;
    const int w = tid >> 6;          // 0..7
    const int wq = w & 3;            // M-slice within the layer group
    const bool isL0 = (w < 4);
    const int n = lane & 15;
    const int q = lane >> 4;
    const int b0 = blockIdx.x * 16;

    // h1(-1) = 0 at parity 1 (read by L1 at s=1)
    if (tid < 512) ((int*)&h1f[1][0])[tid] = 0;

    const int mrow = 16 * wq + n;
    const int m4 = 16 * wq + 4 * q;
    const int rbase = 128 * q + 8 * n;
    const int wbase = (2 * wq + (q >> 1)) * 128 + 8 * n + 4 * (q & 1);

    // ---- per-group weight fragments, single fp16 (RTNE) ----
    half8 wA[2], wB[2];  // L0: A=W_hh0 ; L1: A=W_ih1, B=W_hh1
    auto mkfrag = [&](const float* p, half8& hi) {
#pragma unroll
        for (int j = 0; j < 8; ++j) hi[j] = (_Float16)p[j];  // RTNE
    };
    float4 wih0v = {0, 0, 0, 0}, bv0 = {0, 0, 0, 0}, bv1 = {0, 0, 0, 0}, wfcv = {0, 0, 0, 0};
    if (isL0) {
#pragma unroll
        for (int k = 0; k < 2; ++k)
            mkfrag(W_hh0 + mrow * 64 + 32 * k + 8 * q, wA[k]);
        wih0v = *(const float4*)(W_ih0 + m4);
        bv0 = *(const float4*)(b_ih0 + m4);
        { float4 t = *(const float4*)(b_hh0 + m4); bv0.x += t.x; bv0.y += t.y; bv0.z += t.z; bv0.w += t.w; }
    } else {
#pragma unroll
        for (int k = 0; k < 2; ++k) {
            mkfrag(W_ih1 + mrow * 64 + 32 * k + 8 * q, wA[k]);
            mkfrag(W_hh1 + mrow * 64 + 32 * k + 8 * q, wB[k]);
        }
        bv1 = *(const float4*)(b_ih1 + m4);
        { float4 t = *(const float4*)(b_hh1 + m4); bv1.x += t.x; bv1.y += t.y; bv1.z += t.z; bv1.w += t.w; }
        wfcv = *(const float4*)(W_fc + m4);
    }

    const float* xp = x + (long)(b0 + n) * TT;
    const floatx4 zero4 = {0.f, 0.f, 0.f, 0.f};

    // tanh + fp16 RTNE pack + LDS write (4 rows -> uint2)
    auto epi_write = [&](const floatx4& A, const floatx4& B, short* pf) {
        float h[4];
#pragma unroll
        for (int r = 0; r < 4; ++r) h[r] = fast_tanh(A[r] + B[r]);
        uint2 u;
        u.x = pk16(h[0], h[1]);
        u.y = pk16(h[2], h[3]);
        *(uint2*)&pf[wbase] = u;
    };

    // ---- prologue: L0 waves write h0(0) = tanh(x(0)Wih0 + b0) -> parity 0 ----
    float xv = 0.f, xnext = 0.f;
    if (isL0) {
        const float xv0 = xp[0];
        float h[4];
#pragma unroll
        for (int r = 0; r < 4; ++r)
            h[r] = fast_tanh(__builtin_fmaf(xv0, f4e(wih0v, r), f4e(bv0, r)));
        uint2 u;
        u.x = pk16(h[0], h[1]);
        u.y = pk16(h[2], h[3]);
        *(uint2*)&h0f[0][wbase] = u;
        xv = xp[1];
        xnext = xp[2];
    }
    BAR();

    // L0 superstep: read h0[rp], compute h0(s), write h0[wp]
    auto stepL0 = [&](int rp, int wp, float xvv) {
        half8 b[2];
#pragma unroll
        for (int k = 0; k < 2; ++k)
            b[k] = *(const half8*)&h0f[rp][rbase + 512 * k];
        floatx4 aA = {__builtin_fmaf(xvv, wih0v.x, bv0.x), __builtin_fmaf(xvv, wih0v.y, bv0.y),
                      __builtin_fmaf(xvv, wih0v.z, bv0.z), __builtin_fmaf(xvv, wih0v.w, bv0.w)};
        floatx4 aB = zero4;
        aA = __builtin_amdgcn_mfma_f32_16x16x32_f16(wA[0], b[0], aA, 0, 0, 0);
        aB = __builtin_amdgcn_mfma_f32_16x16x32_f16(wA[1], b[1], aB, 0, 0, 0);
        epi_write(aA, aB, &h0f[wp][0]);
    };

    // L1 superstep: read h0[rp0], h1[rp1], compute h1, write h1[wp1]
    auto stepL1 = [&](int rp0, int rp1, int wp1) {
        half8 b[2], c[2];
#pragma unroll
        for (int k = 0; k < 2; ++k) {
            b[k] = *(const half8*)&h0f[rp0][rbase + 512 * k];
            c[k] = *(const half8*)&h1f[rp1][rbase + 512 * k];
        }
        floatx4 aA = {bv1.x, bv1.y, bv1.z, bv1.w};
        floatx4 aB = zero4;
        // two independent 2-deep chains
        aA = __builtin_amdgcn_mfma_f32_16x16x32_f16(wA[0], b[0], aA, 0, 0, 0);
        aB = __builtin_amdgcn_mfma_f32_16x16x32_f16(wB[0], c[0], aB, 0, 0, 0);
        aA = __builtin_amdgcn_mfma_f32_16x16x32_f16(wA[1], b[1], aA, 0, 0, 0);
        aB = __builtin_amdgcn_mfma_f32_16x16x32_f16(wB[1], c[1], aB, 0, 0, 0);
        epi_write(aA, aB, &h1f[wp1][0]);
    };

    // main loop: pairs (s odd, s+1 even), s = 1..509; tail s = 511
    for (int s = 1; s < 511; s += 2) {
        if (isL0) {
            stepL0(0, 1, xv);
            xv = xnext; xnext = xp[(s + 2) & (TT - 1)];
        } else {
            stepL1(0, 1, 0);
        }
        BAR();
        if (isL0) {
            stepL0(1, 0, xv);
            xv = xnext; xnext = xp[(s + 3) & (TT - 1)];
        } else {
            stepL1(1, 0, 1);
        }
        BAR();
    }
    // s = 511 (odd): L0 h0(511) -> parity 1 ; L1 h1(510) -> parity 0
    if (isL0) stepL0(0, 1, xv);
    else      stepL1(0, 1, 0);
    BAR();

    // ---- tail: L1 waves compute h1(511) + FC dot ----
    float p = 0.f;
    if (!isL0) {
        half8 b[2], c[2];
#pragma unroll
        for (int k = 0; k < 2; ++k) {
            b[k] = *(const half8*)&h0f[1][rbase + 512 * k];  // h0(511), parity 1
            c[k] = *(const half8*)&h1f[0][rbase + 512 * k];  // h1(510), parity 0
        }
        floatx4 aA = {bv1.x, bv1.y, bv1.z, bv1.w};
        floatx4 aB = zero4;
        aA = __builtin_amdgcn_mfma_f32_16x16x32_f16(wA[0], b[0], aA, 0, 0, 0);
        aB = __builtin_amdgcn_mfma_f32_16x16x32_f16(wB[0], c[0], aB, 0, 0, 0);
        aA = __builtin_amdgcn_mfma_f32_16x16x32_f16(wA[1], b[1], aA, 0, 0, 0);
        aB = __builtin_amdgcn_mfma_f32_16x16x32_f16(wB[1], c[1], aB, 0, 0, 0);
#pragma unroll
        for (int r = 0; r < 4; ++r) {
            const float h = fast_tanh(aA[r] + aB[r]);
            p = __builtin_fmaf(h, f4e(wfcv, r), p);
        }
        p += __shfl_xor(p, 16, 64);
        p += __shfl_xor(p, 32, 64);
        if (lane < 16) red[wq][lane] = p;
    }
    __syncthreads();
    if (w == 4 && lane < 16)
        out[b0 + lane] = red[0][lane] + red[1][lane] + red[2][lane] + red[3][lane] + b_fc[0];
}

extern "C" void kernel_launch(void* const* d_in, const int* in_sizes, int n_in,
                              void* d_out, int out_size, void* d_ws, size_t ws_size,
                              hipStream_t stream) {
    const float* x     = (const float*)d_in[0];
    const float* W_ih0 = (const float*)d_in[1];
    const float* W_hh0 = (const float*)d_in[2];
    const float* b_ih0 = (const float*)d_in[3];
    const float* b_hh0 = (const float*)d_in[4];
    const float* W_ih1 = (const float*)d_in[5];
    const float* W_hh1 = (const float*)d_in[6];
    const float* b_ih1 = (const float*)d_in[7];
    const float* b_hh1 = (const float*)d_in[8];
    const float* W_fc  = (const float*)d_in[9];
    const float* b_fc  = (const float*)d_in[10];
    float* out = (float*)d_out;

    rnn2_mfma<<<128, 512, 0, stream>>>(x, W_ih0, W_hh0, b_ih0, b_hh0,
                                       W_ih1, W_hh1, b_ih1, b_hh1,
                                       W_fc, b_fc, out);
}